// Round 1
// baseline (193.281 us; speedup 1.0000x reference)
//
#include <hip/hip_runtime.h>

#define TEMP      4.0f
#define INV_TEMP  0.25f
#define ALPHA     0.7f

__device__ __forceinline__ float waveReduceSum(float v) {
#pragma unroll
    for (int o = 32; o > 0; o >>= 1) v += __shfl_down(v, o, 64);
    return v;
}

// One block (256 threads = 4 waves) per row. Single streaming pass over s,t.
__global__ __launch_bounds__(256) void distill_row_kernel(
    const float* __restrict__ s, const float* __restrict__ t,
    const int* __restrict__ lbl, float* __restrict__ ws, int N, int V)
{
    const int row = blockIdx.x;
    const size_t base = (size_t)row * (size_t)V;
    const float4* __restrict__ s4 = reinterpret_cast<const float4*>(s + base);
    const float4* __restrict__ t4 = reinterpret_cast<const float4*>(t + base);
    const int nvec = V >> 2;

    float zsT = 0.f, zs1 = 0.f, ztT = 0.f, accA = 0.f, accB = 0.f;

    for (int i = threadIdx.x; i < nvec; i += 256) {
        float4 sv = s4[i];
        float4 tv = t4[i];
#pragma unroll
        for (int c = 0; c < 4; ++c) {
            float sx = (&sv.x)[c];
            float tx = (&tv.x)[c];
            float esT = __expf(sx * INV_TEMP);
            float es1 = __expf(sx);
            float etT = __expf(tx * INV_TEMP);
            zsT += esT;
            zs1 += es1;
            ztT += etT;
            accA = fmaf(etT, tx, accA);
            accB = fmaf(etT, sx, accB);
        }
    }
    // tail (V not multiple of 4)
    for (int i = (nvec << 2) + threadIdx.x; i < V; i += 256) {
        float sx = s[base + i];
        float tx = t[base + i];
        float esT = __expf(sx * INV_TEMP);
        float es1 = __expf(sx);
        float etT = __expf(tx * INV_TEMP);
        zsT += esT; zs1 += es1; ztT += etT;
        accA = fmaf(etT, tx, accA);
        accB = fmaf(etT, sx, accB);
    }

    // block reduction: wave shuffle, then LDS across the 4 waves
    __shared__ float red[4][5];
    const int wid  = threadIdx.x >> 6;
    const int lane = threadIdx.x & 63;
    zsT  = waveReduceSum(zsT);
    zs1  = waveReduceSum(zs1);
    ztT  = waveReduceSum(ztT);
    accA = waveReduceSum(accA);
    accB = waveReduceSum(accB);
    if (lane == 0) {
        red[wid][0] = zsT; red[wid][1] = zs1; red[wid][2] = ztT;
        red[wid][3] = accA; red[wid][4] = accB;
    }
    __syncthreads();
    if (threadIdx.x == 0) {
        float ZsT = 0.f, Zs1 = 0.f, ZtT = 0.f, A = 0.f, B = 0.f;
#pragma unroll
        for (int w = 0; w < 4; ++w) {
            ZsT += red[w][0]; Zs1 += red[w][1]; ZtT += red[w][2];
            A   += red[w][3]; B   += red[w][4];
        }
        float kl = (A - B) / (TEMP * ZtT) + logf(ZsT) - logf(ZtT);

        int l = lbl[row];
        float slbl = s[base + (size_t)l];
        float nll = logf(Zs1) - slbl;
        float valid = (l != 0) ? 1.0f : 0.0f;

        ws[row]         = kl;
        ws[N + row]     = nll * valid;
        ws[2 * N + row] = valid;
    }
}

__global__ __launch_bounds__(256) void distill_finalize_kernel(
    const float* __restrict__ ws, float* __restrict__ out, int N)
{
    float kl = 0.f, nll = 0.f, val = 0.f;
    for (int i = threadIdx.x; i < N; i += 256) {
        kl  += ws[i];
        nll += ws[N + i];
        val += ws[2 * N + i];
    }
    __shared__ float red[4][3];
    const int wid  = threadIdx.x >> 6;
    const int lane = threadIdx.x & 63;
    kl  = waveReduceSum(kl);
    nll = waveReduceSum(nll);
    val = waveReduceSum(val);
    if (lane == 0) { red[wid][0] = kl; red[wid][1] = nll; red[wid][2] = val; }
    __syncthreads();
    if (threadIdx.x == 0) {
        float KL = 0.f, NLL = 0.f, VAL = 0.f;
#pragma unroll
        for (int w = 0; w < 4; ++w) { KL += red[w][0]; NLL += red[w][1]; VAL += red[w][2]; }
        float distill = (KL / (float)N) * (TEMP * TEMP);
        float task    = NLL / fmaxf(VAL, 1.0f);
        out[0] = ALPHA * distill + (1.0f - ALPHA) * task;
        out[1] = distill;
        out[2] = task;
    }
}

extern "C" void kernel_launch(void* const* d_in, const int* in_sizes, int n_in,
                              void* d_out, int out_size, void* d_ws, size_t ws_size,
                              hipStream_t stream) {
    const float* s   = (const float*)d_in[0];
    const float* t   = (const float*)d_in[1];
    const int*   lbl = (const int*)d_in[2];
    float* ws  = (float*)d_ws;
    float* out = (float*)d_out;

    const int N = in_sizes[2];             // B*S = 4096
    const int V = in_sizes[0] / N;         // 32000

    distill_row_kernel<<<N, 256, 0, stream>>>(s, t, lbl, ws, N, V);
    distill_finalize_kernel<<<1, 256, 0, stream>>>(ws, out, N);
}

// Round 3
// 163.707 us; speedup vs baseline: 1.1806x; 1.1806x over previous
//
#include <hip/hip_runtime.h>

#define TEMP      4.0f
#define INV_TEMP  0.25f
#define ALPHA     0.7f

typedef float f32x4 __attribute__((ext_vector_type(4)));

__device__ __forceinline__ float waveReduceSum(float v) {
#pragma unroll
    for (int o = 32; o > 0; o >>= 1) v += __shfl_down(v, o, 64);
    return v;
}

// One block (256 threads = 4 waves) per row. Single streaming pass over s,t.
// 2x-unrolled float4 loads (4 outstanding 16B loads/thread) + nontemporal hint.
__global__ __launch_bounds__(256) void distill_row_kernel(
    const float* __restrict__ s, const float* __restrict__ t,
    const int* __restrict__ lbl, float* __restrict__ ws, int N, int V)
{
    const int row = blockIdx.x;
    const size_t base = (size_t)row * (size_t)V;
    const f32x4* __restrict__ s4 = reinterpret_cast<const f32x4*>(s + base);
    const f32x4* __restrict__ t4 = reinterpret_cast<const f32x4*>(t + base);
    const int nvec = V >> 2;

    float zsT = 0.f, zs1 = 0.f, ztT = 0.f, accA = 0.f, accB = 0.f;

#define PROC4(sv, tv)                                   \
    do {                                                \
        _Pragma("unroll")                               \
        for (int c = 0; c < 4; ++c) {                   \
            float sx = (sv)[c];                         \
            float tx = (tv)[c];                         \
            float esT = __expf(sx * INV_TEMP);          \
            float es2 = esT * esT;                      \
            float es1 = es2 * es2;  /* e^s = (e^{s/4})^4 */ \
            float etT = __expf(tx * INV_TEMP);          \
            zsT += esT;                                 \
            zs1 += es1;                                 \
            ztT += etT;                                 \
            accA = fmaf(etT, tx, accA);                 \
            accB = fmaf(etT, sx, accB);                 \
        }                                               \
    } while (0)

    int i = threadIdx.x;
    // paired iterations: 4 outstanding 16B loads before any compute
    for (; i + 256 < nvec; i += 512) {
        f32x4 sv0 = __builtin_nontemporal_load(&s4[i]);
        f32x4 sv1 = __builtin_nontemporal_load(&s4[i + 256]);
        f32x4 tv0 = __builtin_nontemporal_load(&t4[i]);
        f32x4 tv1 = __builtin_nontemporal_load(&t4[i + 256]);
        PROC4(sv0, tv0);
        PROC4(sv1, tv1);
    }
    if (i < nvec) {
        f32x4 sv0 = __builtin_nontemporal_load(&s4[i]);
        f32x4 tv0 = __builtin_nontemporal_load(&t4[i]);
        PROC4(sv0, tv0);
    }
    // scalar tail (V not multiple of 4; zero iterations for V=32000)
    for (int j = (nvec << 2) + threadIdx.x; j < V; j += 256) {
        float sx = s[base + j];
        float tx = t[base + j];
        float esT = __expf(sx * INV_TEMP);
        float es2 = esT * esT;
        float es1 = es2 * es2;
        float etT = __expf(tx * INV_TEMP);
        zsT += esT; zs1 += es1; ztT += etT;
        accA = fmaf(etT, tx, accA);
        accB = fmaf(etT, sx, accB);
    }
#undef PROC4

    // block reduction: wave shuffle, then LDS across the 4 waves
    __shared__ float red[4][5];
    const int wid  = threadIdx.x >> 6;
    const int lane = threadIdx.x & 63;
    zsT  = waveReduceSum(zsT);
    zs1  = waveReduceSum(zs1);
    ztT  = waveReduceSum(ztT);
    accA = waveReduceSum(accA);
    accB = waveReduceSum(accB);
    if (lane == 0) {
        red[wid][0] = zsT; red[wid][1] = zs1; red[wid][2] = ztT;
        red[wid][3] = accA; red[wid][4] = accB;
    }
    __syncthreads();
    if (threadIdx.x == 0) {
        float ZsT = 0.f, Zs1 = 0.f, ZtT = 0.f, A = 0.f, B = 0.f;
#pragma unroll
        for (int w = 0; w < 4; ++w) {
            ZsT += red[w][0]; Zs1 += red[w][1]; ZtT += red[w][2];
            A   += red[w][3]; B   += red[w][4];
        }
        float kl = (A - B) / (TEMP * ZtT) + logf(ZsT) - logf(ZtT);

        int l = lbl[row];
        float slbl = s[base + (size_t)l];
        float nll = logf(Zs1) - slbl;
        float valid = (l != 0) ? 1.0f : 0.0f;

        ws[row]         = kl;
        ws[N + row]     = nll * valid;
        ws[2 * N + row] = valid;
    }
}

__global__ __launch_bounds__(256) void distill_finalize_kernel(
    const float* __restrict__ ws, float* __restrict__ out, int N)
{
    float kl = 0.f, nll = 0.f, val = 0.f;
    for (int i = threadIdx.x; i < N; i += 256) {
        kl  += ws[i];
        nll += ws[N + i];
        val += ws[2 * N + i];
    }
    __shared__ float red[4][3];
    const int wid  = threadIdx.x >> 6;
    const int lane = threadIdx.x & 63;
    kl  = waveReduceSum(kl);
    nll = waveReduceSum(nll);
    val = waveReduceSum(val);
    if (lane == 0) { red[wid][0] = kl; red[wid][1] = nll; red[wid][2] = val; }
    __syncthreads();
    if (threadIdx.x == 0) {
        float KL = 0.f, NLL = 0.f, VAL = 0.f;
#pragma unroll
        for (int w = 0; w < 4; ++w) { KL += red[w][0]; NLL += red[w][1]; VAL += red[w][2]; }
        float distill = (KL / (float)N) * (TEMP * TEMP);
        float task    = NLL / fmaxf(VAL, 1.0f);
        out[0] = ALPHA * distill + (1.0f - ALPHA) * task;
        out[1] = distill;
        out[2] = task;
    }
}

extern "C" void kernel_launch(void* const* d_in, const int* in_sizes, int n_in,
                              void* d_out, int out_size, void* d_ws, size_t ws_size,
                              hipStream_t stream) {
    const float* s   = (const float*)d_in[0];
    const float* t   = (const float*)d_in[1];
    const int*   lbl = (const int*)d_in[2];
    float* ws  = (float*)d_ws;
    float* out = (float*)d_out;

    const int N = in_sizes[2];             // B*S = 4096
    const int V = in_sizes[0] / N;         // 32000

    distill_row_kernel<<<N, 256, 0, stream>>>(s, t, lbl, ws, N, V);
    distill_finalize_kernel<<<1, 256, 0, stream>>>(ws, out, N);
}